// Round 13
// baseline (219.321 us; speedup 1.0000x reference)
//
#include <hip/hip_runtime.h>
#include <math.h>

#define ALPHA_LEAKY 0.2f
#define EPS_F 1e-10f
#define NBMAX 2048   // max buckets (N <= 65536 @ 32 nodes/bucket)
#define NBLK 256     // hist/place chunk blocks
#define CAP  2048    // max bucket segment held in LDS (avg ~512)

typedef __attribute__((ext_vector_type(8))) short short8;   // 8 bf16 (4 VGPRs)
typedef __attribute__((ext_vector_type(4))) float f32x4;    // MFMA C/D frag

__device__ __forceinline__ unsigned short bf16_rne(float f) {
    unsigned u = __float_as_uint(f);
    u += 0x7FFFu + ((u >> 16) & 1u);
    return (unsigned short)(u >> 16);
}

// prep: W -> MFMA B-frags (bf16)
__global__ void k_prep(const float* __restrict__ W, uint4* __restrict__ Wbf) {
    int f = blockIdx.x * 256 + threadIdx.x;
    int nt = f >> 8;
    if (nt >= 4) return;                  // 1024 valid frags
    int l = f & 63, kt = (f >> 6) & 3;
    int nn = nt * 16 + (l & 15);
    int k  = kt * 32 + (l >> 4) * 8;
    const float* wr = W + nn * 128 + k;
    unsigned short b[8];
    #pragma unroll
    for (int j = 0; j < 8; ++j) b[j] = bf16_rne(wr[j]);
    uint4 v;
    v.x = (unsigned)b[0] | ((unsigned)b[1] << 16);
    v.y = (unsigned)b[2] | ((unsigned)b[3] << 16);
    v.z = (unsigned)b[4] | ((unsigned)b[5] << 16);
    v.w = (unsigned)b[6] | ((unsigned)b[7] << 16);
    Wbf[f] = v;
}

// MFMA GEMM + fused scores. One wave per 16-row stripe; W pinned as B-frags
// in 64 VGPRs; A-frags straight from fp32 X; no LDS.
// C/D map: col = lane&15 (ml), row = (lane>>4)*4 + reg.
__global__ __launch_bounds__(256) void k_gemm(
    const float* __restrict__ X, const uint4* __restrict__ Wbf,
    const float* __restrict__ a, unsigned short* __restrict__ hb,
    float* __restrict__ s_src, float* __restrict__ s_tgt, int n, int nstripes) {
    const int lane = threadIdx.x & 63;
    const int ml = lane & 15, g = lane >> 4;
    short8 bfr[4][4];
    #pragma unroll
    for (int nt = 0; nt < 4; ++nt)
        #pragma unroll
        for (int kt = 0; kt < 4; ++kt) {
            uint4 v = Wbf[(nt * 4 + kt) * 64 + lane];
            bfr[nt][kt] = *(short8*)&v;
        }
    float as[4], at[4];
    #pragma unroll
    for (int nt = 0; nt < 4; ++nt) {
        as[nt] = a[nt * 16 + ml];
        at[nt] = a[64 + nt * 16 + ml];
    }
    for (int stripe = blockIdx.x * 4 + (threadIdx.x >> 6); stripe < nstripes;
         stripe += gridDim.x * 4) {
        const int row0 = stripe * 16;
        const int rrow = min(row0 + ml, n - 1);
        const float* xr = X + (size_t)rrow * 128;
        f32x4 acc[4] = {{0.f,0.f,0.f,0.f},{0.f,0.f,0.f,0.f},
                        {0.f,0.f,0.f,0.f},{0.f,0.f,0.f,0.f}};
        #pragma unroll
        for (int kt = 0; kt < 4; ++kt) {
            float4 x0 = *(const float4*)(xr + kt * 32 + g * 8);
            float4 x1 = *(const float4*)(xr + kt * 32 + g * 8 + 4);
            short8 af;
            af[0] = (short)bf16_rne(x0.x); af[1] = (short)bf16_rne(x0.y);
            af[2] = (short)bf16_rne(x0.z); af[3] = (short)bf16_rne(x0.w);
            af[4] = (short)bf16_rne(x1.x); af[5] = (short)bf16_rne(x1.y);
            af[6] = (short)bf16_rne(x1.z); af[7] = (short)bf16_rne(x1.w);
            #pragma unroll
            for (int nt = 0; nt < 4; ++nt)
                acc[nt] = __builtin_amdgcn_mfma_f32_16x16x32_bf16(
                    af, bfr[nt][kt], acc[nt], 0, 0, 0);
        }
        #pragma unroll
        for (int reg = 0; reg < 4; ++reg) {
            int row = row0 + g * 4 + reg;
            float p = acc[0][reg] * as[0] + acc[1][reg] * as[1] +
                      acc[2][reg] * as[2] + acc[3][reg] * as[3];
            float q = acc[0][reg] * at[0] + acc[1][reg] * at[1] +
                      acc[2][reg] * at[2] + acc[3][reg] * at[3];
            #pragma unroll
            for (int off = 1; off < 16; off <<= 1) {
                p += __shfl_xor(p, off, 64);
                q += __shfl_xor(q, off, 64);
            }
            if (ml == 0 && row < n) { s_src[row] = p; s_tgt[row] = q; }
        }
        #pragma unroll
        for (int nt = 0; nt < 4; ++nt)
            #pragma unroll
            for (int reg = 0; reg < 4; ++reg) {
                int row = row0 + g * 4 + reg;
                if (row < n)
                    hb[(size_t)row * 64 + nt * 16 + ml] = bf16_rne(acc[nt][reg]);
            }
    }
}

// counting-sort pass 1: per-block LDS histogram of bucket = tgt>>5.
// Block 0 also resets the done-counter used by k_scan's last-block pattern.
__global__ __launch_bounds__(256) void k_hist(
    const int* __restrict__ ei, int* __restrict__ histg, int* __restrict__ done,
    int nb, int E, int epb) {
    __shared__ int hist[NBMAX];
    const int t = threadIdx.x;
    if (blockIdx.x == 0 && t == 0) atomicExch(done, 0);
    for (int k = t; k < nb; k += 256) hist[k] = 0;
    __syncthreads();
    const int e0 = blockIdx.x * epb, e1 = min(e0 + epb, E);
    for (int e = e0 + t; e < e1; e += 256)
        atomicAdd(&hist[ei[E + e] >> 5], 1);
    __syncthreads();
    int* outp = histg + (size_t)blockIdx.x * nb;
    for (int k = t; k < nb; k += 256) outp[k] = hist[k];
}

// merged colscan + bscan: per-bucket exclusive scan over the NBLK block
// counts (one block per bucket); the LAST block to finish additionally scans
// the bucket totals into bstart (deterministic; device-scope atomics+fences).
__global__ __launch_bounds__(256) void k_scan(
    int* __restrict__ histg, int* __restrict__ btot, int* __restrict__ bstart,
    int* __restrict__ done, int nb, int E) {
    __shared__ int wsum[4];
    __shared__ int lastflag;
    const int bucket = blockIdx.x;
    const int t = threadIdx.x, lane = t & 63, w = t >> 6;
    int v = histg[(size_t)t * nb + bucket];
    int pre = v;
    #pragma unroll
    for (int off = 1; off < 64; off <<= 1) {
        int x = __shfl_up(pre, off, 64);
        if (lane >= off) pre += x;
    }
    if (lane == 63) wsum[w] = pre;
    __syncthreads();
    int wb = 0;
    for (int k = 0; k < w; ++k) wb += wsum[k];
    histg[(size_t)t * nb + bucket] = wb + pre - v;   // exclusive
    if (t == 255) atomicExch(&btot[bucket], wb + pre);
    __syncthreads();
    if (t == 0) {
        __threadfence();
        lastflag = (atomicAdd(done, 1) == nb - 1) ? 1 : 0;
    }
    __syncthreads();
    if (!lastflag) return;
    __threadfence();
    // bscan over nb totals (nb <= 2048 -> 8 per thread)
    int tv[8]; int sum = 0;
    #pragma unroll
    for (int j = 0; j < 8; ++j) {
        int idx = t * 8 + j;
        tv[j] = (idx < nb) ? atomicAdd(&btot[idx], 0) : 0;
        sum += tv[j];
    }
    int p2 = sum;
    #pragma unroll
    for (int off = 1; off < 64; off <<= 1) {
        int x = __shfl_up(p2, off, 64);
        if (lane >= off) p2 += x;
    }
    if (lane == 63) wsum[w] = p2;
    __syncthreads();
    int wb2 = 0;
    for (int k = 0; k < w; ++k) wb2 += wsum[k];
    int run = wb2 + p2 - sum;
    #pragma unroll
    for (int j = 0; j < 8; ++j) {
        int idx = t * 8 + j;
        if (idx < nb) bstart[idx] = run;
        run += tv[j];
    }
    if (t == 255) bstart[nb] = E;
}

// counting-sort pass 2: place packed edge (s<<5 | tgt&31) into bucket regions
// via LDS cursors seeded from scanned offsets. Zero global atomics.
__global__ __launch_bounds__(256) void k_place(
    const int* __restrict__ ei, const int* __restrict__ histg,
    const int* __restrict__ bstart, unsigned* __restrict__ st,
    int nb, int E, int epb) {
    __shared__ int cur[NBMAX];
    const int t = threadIdx.x;
    const int* my = histg + (size_t)blockIdx.x * nb;
    for (int k = t; k < nb; k += 256) cur[k] = bstart[k] + my[k];
    __syncthreads();
    const int e0 = blockIdx.x * epb, e1 = min(e0 + epb, E);
    for (int e = e0 + t; e < e1; e += 256) {
        int s  = ei[e];
        int tt = ei[E + e];
        int slot = atomicAdd(&cur[tt >> 5], 1);
        st[slot] = ((unsigned)s << 5) | (unsigned)(tt & 31);
    }
}

// fused per-bucket: in-LDS node sort + per-wave softmax/aggregation/ELU.
// One block per bucket (32 nodes, 4 waves x 8 nodes). Segment entries held
// in registers during the histogram pass, scattered node-sorted into LDS,
// then consumed with the register/shuffle pipeline (8 edges in flight).
__device__ __forceinline__ void accum8(float acc[8], uint4 hv, float w) {
    unsigned u[4] = {hv.x, hv.y, hv.z, hv.w};
    #pragma unroll
    for (int i = 0; i < 4; ++i) {
        float lo = __uint_as_float(u[i] << 16);
        float hi = __uint_as_float(u[i] & 0xFFFF0000u);
        acc[2 * i]     = fmaf(w, lo, acc[2 * i]);
        acc[2 * i + 1] = fmaf(w, hi, acc[2 * i + 1]);
    }
}

__global__ __launch_bounds__(256) void k_bnode2(
    const unsigned* __restrict__ st, const int* __restrict__ bstart,
    const float* __restrict__ s_src, const float* __restrict__ s_tgt,
    const unsigned short* __restrict__ hb, float* __restrict__ out, int n) {
    __shared__ int st_lds[CAP];      // after sort: src per edge, node-grouped
    __shared__ int hist[32];
    __shared__ int base_lds[32];
    __shared__ int deg_lds[32];
    __shared__ int cur[32];
    __shared__ float stgt_lds[32];
    const int b = blockIdx.x;
    const int n0 = b << 5;
    const int t = threadIdx.x;
    const int lane = t & 63;
    const int w = t >> 6;
    const int g = lane >> 3, r = lane & 7;
    const int s0 = bstart[b], seg = bstart[b + 1] - s0;

    if (t < 32) {
        hist[t] = 0;
        int node = n0 + t;
        stgt_lds[t] = (node < n) ? s_tgt[node] : 0.f;
    }
    __syncthreads();

    if (seg <= CAP) {
        // ---- load segment into registers + LDS histogram ----
        unsigned mine[8];
        #pragma unroll
        for (int j = 0; j < 8; ++j) {
            int i = t + j * 256;
            mine[j] = 0xFFFFFFFFu;
            if (i < seg) {
                unsigned p = st[s0 + i];
                mine[j] = p;
                atomicAdd(&hist[p & 31u], 1);
            }
        }
        __syncthreads();
        // ---- scan (first 32 lanes of wave 0) -> base/deg/cursors ----
        if (t < 32) {
            int v = hist[t];
            int pre = v;
            #pragma unroll
            for (int off = 1; off < 32; off <<= 1) {
                int x = __shfl_up(pre, off, 64);
                if (t >= off) pre += x;
            }
            int bs = pre - v;          // exclusive, segment-local
            base_lds[t] = bs;
            deg_lds[t] = v;
            cur[t] = bs;
        }
        __syncthreads();
        // ---- scatter node-sorted into LDS ----
        #pragma unroll
        for (int j = 0; j < 8; ++j) {
            if (mine[j] != 0xFFFFFFFFu) {
                int slot = atomicAdd(&cur[mine[j] & 31u], 1);
                st_lds[slot] = (int)(mine[j] >> 5);
            }
        }
        __syncthreads();

        // ---- per-wave aggregation: 8 nodes each ----
        for (int nl = w * 8; nl < w * 8 + 8; ++nl) {
            const int node = n0 + nl;
            const int bb = base_lds[nl];
            const int d = deg_lds[nl];
            const float stg = stgt_lds[nl];
            float acc[8] = {0.f,0.f,0.f,0.f,0.f,0.f,0.f,0.f};
            if (d <= 64) {
                int src_l = 0; float v = -INFINITY;
                if (lane < d) {
                    src_l = st_lds[bb + lane];
                    float x = s_src[src_l] + stg;
                    v = (x > 0.f) ? x : ALPHA_LEAKY * x;
                }
                float m = v;
                #pragma unroll
                for (int off = 32; off > 0; off >>= 1) m = fmaxf(m, __shfl_xor(m, off, 64));
                float ex = (lane < d) ? expf(v - m) : 0.f;
                float sum = ex;
                #pragma unroll
                for (int off = 32; off > 0; off >>= 1) sum += __shfl_xor(sum, off, 64);
                float w_l = ex * (1.f / (sum + EPS_F));
                for (int k = 0; k < d; k += 8) {
                    int ke = k + g;
                    int s    = __shfl(src_l, ke, 64);
                    float wv = __shfl(w_l,  ke, 64);
                    uint4 hv = ((const uint4*)(hb + (size_t)s * 64))[r];
                    accum8(acc, hv, wv);
                }
            } else {
                float m = -INFINITY;
                for (int c = lane; c < d; c += 64) {
                    float x = s_src[st_lds[bb + c]] + stg;
                    x = (x > 0.f) ? x : ALPHA_LEAKY * x;
                    m = fmaxf(m, x);
                }
                #pragma unroll
                for (int off = 32; off > 0; off >>= 1) m = fmaxf(m, __shfl_xor(m, off, 64));
                float sum = 0.f;
                for (int c = lane; c < d; c += 64) {
                    float x = s_src[st_lds[bb + c]] + stg;
                    x = (x > 0.f) ? x : ALPHA_LEAKY * x;
                    sum += expf(x - m);
                }
                #pragma unroll
                for (int off = 32; off > 0; off >>= 1) sum += __shfl_xor(sum, off, 64);
                float inv = 1.f / (sum + EPS_F);
                for (int c0 = 0; c0 < d; c0 += 64) {
                    int j = c0 + lane;
                    int src_l = 0; float w_l = 0.f;
                    if (j < d) {
                        src_l = st_lds[bb + j];
                        float x = s_src[src_l] + stg;
                        x = (x > 0.f) ? x : ALPHA_LEAKY * x;
                        w_l = expf(x - m) * inv;
                    }
                    int lim = min(64, d - c0);
                    for (int k = 0; k < lim; k += 8) {
                        int ke = k + g;
                        int s    = __shfl(src_l, ke, 64);
                        float wv = __shfl(w_l,  ke, 64);
                        uint4 hv = ((const uint4*)(hb + (size_t)s * 64))[r];
                        accum8(acc, hv, wv);
                    }
                }
            }
            #pragma unroll
            for (int off = 8; off <= 32; off <<= 1) {
                #pragma unroll
                for (int j = 0; j < 8; ++j) acc[j] += __shfl_xor(acc[j], off, 64);
            }
            if (g == 0 && node < n) {
                float4 o0, o1;
                o0.x = acc[0] > 0.f ? acc[0] : expf(acc[0]) - 1.f;
                o0.y = acc[1] > 0.f ? acc[1] : expf(acc[1]) - 1.f;
                o0.z = acc[2] > 0.f ? acc[2] : expf(acc[2]) - 1.f;
                o0.w = acc[3] > 0.f ? acc[3] : expf(acc[3]) - 1.f;
                o1.x = acc[4] > 0.f ? acc[4] : expf(acc[4]) - 1.f;
                o1.y = acc[5] > 0.f ? acc[5] : expf(acc[5]) - 1.f;
                o1.z = acc[6] > 0.f ? acc[6] : expf(acc[6]) - 1.f;
                o1.w = acc[7] > 0.f ? acc[7] : expf(acc[7]) - 1.f;
                float4* o4 = (float4*)out + (size_t)node * 16;
                o4[r * 2]     = o0;
                o4[r * 2 + 1] = o1;
            }
        }
    } else {
        // ---- rare fallback (seg > CAP): filtered passes over global st ----
        for (int nl = w * 8; nl < w * 8 + 8; ++nl) {
            const int node = n0 + nl;
            if (node >= n) continue;
            const float stg = stgt_lds[nl];
            float m = -INFINITY;
            for (int c = lane; c < seg; c += 64) {
                unsigned p = st[s0 + c];
                if ((int)(p & 31u) == nl) {
                    float x = s_src[p >> 5] + stg;
                    x = (x > 0.f) ? x : ALPHA_LEAKY * x;
                    m = fmaxf(m, x);
                }
            }
            #pragma unroll
            for (int off = 32; off > 0; off >>= 1) m = fmaxf(m, __shfl_xor(m, off, 64));
            float sum = 0.f;
            for (int c = lane; c < seg; c += 64) {
                unsigned p = st[s0 + c];
                if ((int)(p & 31u) == nl) {
                    float x = s_src[p >> 5] + stg;
                    x = (x > 0.f) ? x : ALPHA_LEAKY * x;
                    sum += expf(x - m);
                }
            }
            #pragma unroll
            for (int off = 32; off > 0; off >>= 1) sum += __shfl_xor(sum, off, 64);
            float inv = 1.f / (sum + EPS_F);
            float acc[8] = {0.f,0.f,0.f,0.f,0.f,0.f,0.f,0.f};
            for (int c0 = 0; c0 < seg; c0 += 64) {
                int j = c0 + lane;
                int src_l = 0; float w_l = 0.f;
                if (j < seg) {
                    unsigned p = st[s0 + j];
                    if ((int)(p & 31u) == nl) {
                        src_l = p >> 5;
                        float x = s_src[src_l] + stg;
                        x = (x > 0.f) ? x : ALPHA_LEAKY * x;
                        w_l = expf(x - m) * inv;
                    }
                }
                int lim = min(64, seg - c0);
                for (int k = 0; k < lim; k += 8) {
                    int ke = k + g;
                    int s    = __shfl(src_l, ke, 64);
                    float wv = __shfl(w_l,  ke, 64);
                    uint4 hv = ((const uint4*)(hb + (size_t)s * 64))[r];
                    accum8(acc, hv, wv);
                }
            }
            #pragma unroll
            for (int off = 8; off <= 32; off <<= 1) {
                #pragma unroll
                for (int j = 0; j < 8; ++j) acc[j] += __shfl_xor(acc[j], off, 64);
            }
            if (g == 0) {
                float4 o0, o1;
                o0.x = acc[0] > 0.f ? acc[0] : expf(acc[0]) - 1.f;
                o0.y = acc[1] > 0.f ? acc[1] : expf(acc[1]) - 1.f;
                o0.z = acc[2] > 0.f ? acc[2] : expf(acc[2]) - 1.f;
                o0.w = acc[3] > 0.f ? acc[3] : expf(acc[3]) - 1.f;
                o1.x = acc[4] > 0.f ? acc[4] : expf(acc[4]) - 1.f;
                o1.y = acc[5] > 0.f ? acc[5] : expf(acc[5]) - 1.f;
                o1.z = acc[6] > 0.f ? acc[6] : expf(acc[6]) - 1.f;
                o1.w = acc[7] > 0.f ? acc[7] : expf(acc[7]) - 1.f;
                float4* o4 = (float4*)out + (size_t)node * 16;
                o4[r * 2]     = o0;
                o4[r * 2 + 1] = o1;
            }
        }
    }
}

extern "C" void kernel_launch(void* const* d_in, const int* in_sizes, int n_in,
                              void* d_out, int out_size, void* d_ws, size_t ws_size,
                              hipStream_t stream) {
    const float* X  = (const float*)d_in[0];   // [N,128]
    const int*   ei = (const int*)d_in[1];     // [2,E]
    const float* W  = (const float*)d_in[2];   // [64,128]
    const float* a  = (const float*)d_in[3];   // [1,128]
    float* out = (float*)d_out;                // [N,64]

    const int N = in_sizes[0] / 128;
    const int E = in_sizes[1] / 2;
    const int nb = (N + 31) >> 5;              // buckets of 32 nodes (<=2048)
    const int epb = (E + NBLK - 1) / NBLK;

    char* p = (char*)d_ws;
    unsigned short* hb = (unsigned short*)p; p += (size_t)N * 64 * sizeof(unsigned short);
    uint4*    Wbf    = (uint4*)p;    p += 1024 * sizeof(uint4);
    float*    s_src  = (float*)p;    p += (size_t)N * sizeof(float);
    float*    s_tgt  = (float*)p;    p += (size_t)N * sizeof(float);
    int*      histg  = (int*)p;      p += (size_t)NBLK * nb * sizeof(int);
    int*      btot   = (int*)p;      p += (size_t)nb * sizeof(int);
    int*      bstart = (int*)p;      p += (size_t)(nb + 1) * sizeof(int);
    int*      done   = (int*)p;      p += 4 * sizeof(int);
    unsigned* st     = (unsigned*)p;

    const int nstripes = (N + 15) / 16;
    k_prep  <<<4, 256, 0, stream>>>(W, Wbf);
    k_gemm  <<<(nstripes + 3) / 4, 256, 0, stream>>>(X, Wbf, a, hb, s_src, s_tgt, N, nstripes);
    k_hist  <<<NBLK, 256, 0, stream>>>(ei, histg, done, nb, E, epb);
    k_scan  <<<nb, 256, 0, stream>>>(histg, btot, bstart, done, nb, E);
    k_place <<<NBLK, 256, 0, stream>>>(ei, histg, bstart, st, nb, E, epb);
    k_bnode2<<<nb, 256, 0, stream>>>(st, bstart, s_src, s_tgt, hb, out, N);
}

// Round 14
// 148.480 us; speedup vs baseline: 1.4771x; 1.4771x over previous
//
#include <hip/hip_runtime.h>
#include <math.h>

#define ALPHA_LEAKY 0.2f
#define EPS_F 1e-10f
#define NBMAX 1024   // max buckets (N <= 65536)
#define NBLK 256     // hist/place chunk blocks

typedef __attribute__((ext_vector_type(8))) short short8;   // 8 bf16 (4 VGPRs)
typedef __attribute__((ext_vector_type(4))) float f32x4;    // MFMA C/D frag

__device__ __forceinline__ unsigned short bf16_rne(float f) {
    unsigned u = __float_as_uint(f);
    u += 0x7FFFu + ((u >> 16) & 1u);
    return (unsigned short)(u >> 16);
}

// prep: W -> MFMA B-frags (bf16)
__global__ void k_prep(const float* __restrict__ W, uint4* __restrict__ Wbf) {
    int f = blockIdx.x * 256 + threadIdx.x;
    int nt = f >> 8;
    if (nt >= 4) return;                  // 1024 valid frags
    int l = f & 63, kt = (f >> 6) & 3;
    int nn = nt * 16 + (l & 15);
    int k  = kt * 32 + (l >> 4) * 8;
    const float* wr = W + nn * 128 + k;
    unsigned short b[8];
    #pragma unroll
    for (int j = 0; j < 8; ++j) b[j] = bf16_rne(wr[j]);
    uint4 v;
    v.x = (unsigned)b[0] | ((unsigned)b[1] << 16);
    v.y = (unsigned)b[2] | ((unsigned)b[3] << 16);
    v.z = (unsigned)b[4] | ((unsigned)b[5] << 16);
    v.w = (unsigned)b[6] | ((unsigned)b[7] << 16);
    Wbf[f] = v;
}

// MFMA GEMM + fused scores. One wave per 16-row stripe; W pinned as B-frags
// in 64 VGPRs; A-frags straight from fp32 X; no LDS.
// C/D map: col = lane&15 (ml), row = (lane>>4)*4 + reg.
__global__ __launch_bounds__(256) void k_gemm(
    const float* __restrict__ X, const uint4* __restrict__ Wbf,
    const float* __restrict__ a, unsigned short* __restrict__ hb,
    float* __restrict__ s_src, float* __restrict__ s_tgt, int n, int nstripes) {
    const int lane = threadIdx.x & 63;
    const int ml = lane & 15, g = lane >> 4;
    short8 bfr[4][4];
    #pragma unroll
    for (int nt = 0; nt < 4; ++nt)
        #pragma unroll
        for (int kt = 0; kt < 4; ++kt) {
            uint4 v = Wbf[(nt * 4 + kt) * 64 + lane];
            bfr[nt][kt] = *(short8*)&v;
        }
    float as[4], at[4];
    #pragma unroll
    for (int nt = 0; nt < 4; ++nt) {
        as[nt] = a[nt * 16 + ml];
        at[nt] = a[64 + nt * 16 + ml];
    }
    for (int stripe = blockIdx.x * 4 + (threadIdx.x >> 6); stripe < nstripes;
         stripe += gridDim.x * 4) {
        const int row0 = stripe * 16;
        const int rrow = min(row0 + ml, n - 1);
        const float* xr = X + (size_t)rrow * 128;
        f32x4 acc[4] = {{0.f,0.f,0.f,0.f},{0.f,0.f,0.f,0.f},
                        {0.f,0.f,0.f,0.f},{0.f,0.f,0.f,0.f}};
        #pragma unroll
        for (int kt = 0; kt < 4; ++kt) {
            float4 x0 = *(const float4*)(xr + kt * 32 + g * 8);
            float4 x1 = *(const float4*)(xr + kt * 32 + g * 8 + 4);
            short8 af;
            af[0] = (short)bf16_rne(x0.x); af[1] = (short)bf16_rne(x0.y);
            af[2] = (short)bf16_rne(x0.z); af[3] = (short)bf16_rne(x0.w);
            af[4] = (short)bf16_rne(x1.x); af[5] = (short)bf16_rne(x1.y);
            af[6] = (short)bf16_rne(x1.z); af[7] = (short)bf16_rne(x1.w);
            #pragma unroll
            for (int nt = 0; nt < 4; ++nt)
                acc[nt] = __builtin_amdgcn_mfma_f32_16x16x32_bf16(
                    af, bfr[nt][kt], acc[nt], 0, 0, 0);
        }
        #pragma unroll
        for (int reg = 0; reg < 4; ++reg) {
            int row = row0 + g * 4 + reg;
            float p = acc[0][reg] * as[0] + acc[1][reg] * as[1] +
                      acc[2][reg] * as[2] + acc[3][reg] * as[3];
            float q = acc[0][reg] * at[0] + acc[1][reg] * at[1] +
                      acc[2][reg] * at[2] + acc[3][reg] * at[3];
            #pragma unroll
            for (int off = 1; off < 16; off <<= 1) {
                p += __shfl_xor(p, off, 64);
                q += __shfl_xor(q, off, 64);
            }
            if (ml == 0 && row < n) { s_src[row] = p; s_tgt[row] = q; }
        }
        #pragma unroll
        for (int nt = 0; nt < 4; ++nt)
            #pragma unroll
            for (int reg = 0; reg < 4; ++reg) {
                int row = row0 + g * 4 + reg;
                if (row < n)
                    hb[(size_t)row * 64 + nt * 16 + ml] = bf16_rne(acc[nt][reg]);
            }
    }
}

// counting-sort pass 1: per-block LDS histogram of bucket = tgt>>6.
__global__ __launch_bounds__(256) void k_hist(
    const int* __restrict__ ei, int* __restrict__ histg, int nb, int E, int epb) {
    __shared__ int hist[NBMAX];
    const int t = threadIdx.x;
    for (int k = t; k < nb; k += 256) hist[k] = 0;
    __syncthreads();
    const int e0 = blockIdx.x * epb, e1 = min(e0 + epb, E);
    for (int e = e0 + t; e < e1; e += 256)
        atomicAdd(&hist[ei[E + e] >> 6], 1);
    __syncthreads();
    int* outp = histg + (size_t)blockIdx.x * nb;
    for (int k = t; k < nb; k += 256) outp[k] = hist[k];
}

// per-bucket exclusive scan over the NBLK block counts (one block per bucket)
__global__ __launch_bounds__(256) void k_colscan(
    int* __restrict__ histg, int* __restrict__ btot, int nb) {
    __shared__ int wsum[4];
    const int bucket = blockIdx.x;
    const int t = threadIdx.x, lane = t & 63, w = t >> 6;
    int v = histg[(size_t)t * nb + bucket];
    int pre = v;
    #pragma unroll
    for (int off = 1; off < 64; off <<= 1) {
        int x = __shfl_up(pre, off, 64);
        if (lane >= off) pre += x;
    }
    if (lane == 63) wsum[w] = pre;
    __syncthreads();
    int wb = 0;
    for (int k = 0; k < w; ++k) wb += wsum[k];
    histg[(size_t)t * nb + bucket] = wb + pre - v;   // exclusive
    if (t == 255) btot[bucket] = wb + pre;
}

// single-block exclusive scan of bucket totals -> bstart (nb <= 1024)
__global__ __launch_bounds__(256) void k_bscan(
    const int* __restrict__ btot, int* __restrict__ bstart, int nb, int E) {
    __shared__ int wsum[4];
    int t = threadIdx.x;
    int lane = t & 63, w = t >> 6;
    int v[4]; int sum = 0;
    #pragma unroll
    for (int j = 0; j < 4; ++j) {
        int idx = t * 4 + j;
        v[j] = (idx < nb) ? btot[idx] : 0;
        sum += v[j];
    }
    int pre = sum;
    #pragma unroll
    for (int off = 1; off < 64; off <<= 1) {
        int x = __shfl_up(pre, off, 64);
        if (lane >= off) pre += x;
    }
    if (lane == 63) wsum[w] = pre;
    __syncthreads();
    int wbase = 0;
    for (int k = 0; k < w; ++k) wbase += wsum[k];
    int run = wbase + pre - sum;
    #pragma unroll
    for (int j = 0; j < 4; ++j) {
        int idx = t * 4 + j;
        if (idx < nb) bstart[idx] = run;
        run += v[j];
    }
    if (t == 255) bstart[nb] = E;
}

// counting-sort pass 2: place packed edge (s<<6 | tgt&63) into bucket regions
// via LDS cursors seeded from scanned offsets. Zero global atomics.
__global__ __launch_bounds__(256) void k_place(
    const int* __restrict__ ei, const int* __restrict__ histg,
    const int* __restrict__ bstart, unsigned* __restrict__ st,
    int nb, int E, int epb) {
    __shared__ int cur[NBMAX];
    const int t = threadIdx.x;
    const int* my = histg + (size_t)blockIdx.x * nb;
    for (int k = t; k < nb; k += 256) cur[k] = bstart[k] + my[k];
    __syncthreads();
    const int e0 = blockIdx.x * epb, e1 = min(e0 + epb, E);
    for (int e = e0 + t; e < e1; e += 256) {
        int s  = ei[e];
        int tt = ei[E + e];
        int slot = atomicAdd(&cur[tt >> 6], 1);
        st[slot] = ((unsigned)s << 6) | (unsigned)(tt & 63);
    }
}

// per-bucket local sort: LDS histogram of the 64 nodes -> deterministic
// base/deg; LDS-cursor placement writes csr_src into a contiguous region.
__global__ __launch_bounds__(256) void k_local(
    const unsigned* __restrict__ st, const int* __restrict__ bstart,
    int* __restrict__ base, int* __restrict__ deg, int* __restrict__ csr_src,
    int n) {
    __shared__ int hist[64];
    __shared__ int nbase[64];
    const int b = blockIdx.x;
    const int n0 = b << 6;
    const int t = threadIdx.x;
    if (t < 64) hist[t] = 0;
    __syncthreads();
    const int s0 = bstart[b], s1 = bstart[b + 1];
    for (int i = s0 + t; i < s1; i += 256)
        atomicAdd(&hist[st[i] & 63u], 1);
    __syncthreads();
    if (t < 64) {
        int v = hist[t];
        int pre = v;
        #pragma unroll
        for (int off = 1; off < 64; off <<= 1) {
            int x = __shfl_up(pre, off, 64);
            if (t >= off) pre += x;
        }
        int bs = s0 + pre - v;       // exclusive
        nbase[t] = bs;
        if (n0 + t < n) { base[n0 + t] = bs; deg[n0 + t] = v; }
    }
    __syncthreads();
    if (t < 64) hist[t] = nbase[t];  // reuse as cursors
    __syncthreads();
    for (int i = s0 + t; i < s1; i += 256) {
        unsigned p = st[i];
        int slot = atomicAdd(&hist[p & 63u], 1);
        csr_src[slot] = (int)(p >> 6);
    }
}

// per-node softmax + aggregation + ELU (one wave per node; lane = (g,r);
// 8 edges per step, each group reads one 128 B bf16 row as uint4).
__device__ __forceinline__ void accum8(float acc[8], uint4 hv, float w) {
    unsigned u[4] = {hv.x, hv.y, hv.z, hv.w};
    #pragma unroll
    for (int i = 0; i < 4; ++i) {
        float lo = __uint_as_float(u[i] << 16);
        float hi = __uint_as_float(u[i] & 0xFFFF0000u);
        acc[2 * i]     = fmaf(w, lo, acc[2 * i]);
        acc[2 * i + 1] = fmaf(w, hi, acc[2 * i + 1]);
    }
}

__global__ __launch_bounds__(256) void k_node(
    const int* __restrict__ base, const int* __restrict__ deg,
    const int* __restrict__ csr_src, const float* __restrict__ s_src,
    const float* __restrict__ s_tgt, const unsigned short* __restrict__ hb,
    float* __restrict__ out, int n) {
    const int lane = threadIdx.x & 63;
    const int node = blockIdx.x * 4 + (threadIdx.x >> 6);
    if (node >= n) return;
    const int b = base[node];
    const int d = deg[node];
    const float st = s_tgt[node];
    const int g = lane >> 3, r = lane & 7;
    float acc[8] = {0.f, 0.f, 0.f, 0.f, 0.f, 0.f, 0.f, 0.f};

    if (d <= 64) {
        int src_l = 0; float w_l = 0.f, v = -INFINITY;
        if (lane < d) {
            src_l = csr_src[b + lane];
            float x = s_src[src_l] + st;
            v = (x > 0.f) ? x : ALPHA_LEAKY * x;
        }
        float m = v;
        #pragma unroll
        for (int off = 32; off > 0; off >>= 1) m = fmaxf(m, __shfl_xor(m, off, 64));
        float ex = (lane < d) ? expf(v - m) : 0.f;
        float sum = ex;
        #pragma unroll
        for (int off = 32; off > 0; off >>= 1) sum += __shfl_xor(sum, off, 64);
        w_l = ex * (1.f / (sum + EPS_F));
        for (int k = 0; k < d; k += 8) {
            int ke = k + g;
            int s   = __shfl(src_l, ke, 64);
            float w = __shfl(w_l,  ke, 64);
            uint4 hv = ((const uint4*)(hb + (size_t)s * 64))[r];
            accum8(acc, hv, w);
        }
    } else {
        float m = -INFINITY;
        for (int c = lane; c < d; c += 64) {
            float x = s_src[csr_src[b + c]] + st;
            x = (x > 0.f) ? x : ALPHA_LEAKY * x;
            m = fmaxf(m, x);
        }
        #pragma unroll
        for (int off = 32; off > 0; off >>= 1) m = fmaxf(m, __shfl_xor(m, off, 64));
        float sum = 0.f;
        for (int c = lane; c < d; c += 64) {
            float x = s_src[csr_src[b + c]] + st;
            x = (x > 0.f) ? x : ALPHA_LEAKY * x;
            sum += expf(x - m);
        }
        #pragma unroll
        for (int off = 32; off > 0; off >>= 1) sum += __shfl_xor(sum, off, 64);
        float inv = 1.f / (sum + EPS_F);
        for (int c0 = 0; c0 < d; c0 += 64) {
            int j = c0 + lane;
            int src_l = 0; float w_l = 0.f;
            if (j < d) {
                src_l = csr_src[b + j];
                float x = s_src[src_l] + st;
                x = (x > 0.f) ? x : ALPHA_LEAKY * x;
                w_l = expf(x - m) * inv;
            }
            int lim = min(64, d - c0);
            for (int k = 0; k < lim; k += 8) {
                int ke = k + g;
                int s   = __shfl(src_l, ke, 64);
                float w = __shfl(w_l,  ke, 64);
                uint4 hv = ((const uint4*)(hb + (size_t)s * 64))[r];
                accum8(acc, hv, w);
            }
        }
    }

    #pragma unroll
    for (int off = 8; off <= 32; off <<= 1) {
        #pragma unroll
        for (int j = 0; j < 8; ++j) acc[j] += __shfl_xor(acc[j], off, 64);
    }
    if (g == 0) {
        float4 o0, o1;
        o0.x = acc[0] > 0.f ? acc[0] : expf(acc[0]) - 1.f;
        o0.y = acc[1] > 0.f ? acc[1] : expf(acc[1]) - 1.f;
        o0.z = acc[2] > 0.f ? acc[2] : expf(acc[2]) - 1.f;
        o0.w = acc[3] > 0.f ? acc[3] : expf(acc[3]) - 1.f;
        o1.x = acc[4] > 0.f ? acc[4] : expf(acc[4]) - 1.f;
        o1.y = acc[5] > 0.f ? acc[5] : expf(acc[5]) - 1.f;
        o1.z = acc[6] > 0.f ? acc[6] : expf(acc[6]) - 1.f;
        o1.w = acc[7] > 0.f ? acc[7] : expf(acc[7]) - 1.f;
        float4* o4 = (float4*)out + (size_t)node * 16;
        o4[r * 2]     = o0;
        o4[r * 2 + 1] = o1;
    }
}

extern "C" void kernel_launch(void* const* d_in, const int* in_sizes, int n_in,
                              void* d_out, int out_size, void* d_ws, size_t ws_size,
                              hipStream_t stream) {
    const float* X  = (const float*)d_in[0];   // [N,128]
    const int*   ei = (const int*)d_in[1];     // [2,E]
    const float* W  = (const float*)d_in[2];   // [64,128]
    const float* a  = (const float*)d_in[3];   // [1,128]
    float* out = (float*)d_out;                // [N,64]

    const int N = in_sizes[0] / 128;
    const int E = in_sizes[1] / 2;
    const int nb = (N + 63) >> 6;              // buckets of 64 nodes (<=1024)
    const int epb = (E + NBLK - 1) / NBLK;

    char* p = (char*)d_ws;
    unsigned short* hb = (unsigned short*)p; p += (size_t)N * 64 * sizeof(unsigned short);
    uint4*    Wbf    = (uint4*)p;    p += 1024 * sizeof(uint4);
    float*    s_src  = (float*)p;    p += (size_t)N * sizeof(float);
    float*    s_tgt  = (float*)p;    p += (size_t)N * sizeof(float);
    int*      deg    = (int*)p;      p += (size_t)N * sizeof(int);
    int*      base   = (int*)p;      p += (size_t)N * sizeof(int);
    int*      histg  = (int*)p;      p += (size_t)NBLK * nb * sizeof(int);
    int*      btot   = (int*)p;      p += (size_t)nb * sizeof(int);
    int*      bstart = (int*)p;      p += (size_t)(nb + 1) * sizeof(int);
    int*      csr_src= (int*)p;      p += (size_t)E * sizeof(int);
    unsigned* st     = (unsigned*)p;

    const int nstripes = (N + 15) / 16;
    k_prep   <<<4, 256, 0, stream>>>(W, Wbf);
    k_gemm   <<<(nstripes + 3) / 4, 256, 0, stream>>>(X, Wbf, a, hb, s_src, s_tgt, N, nstripes);
    k_hist   <<<NBLK, 256, 0, stream>>>(ei, histg, nb, E, epb);
    k_colscan<<<nb, 256, 0, stream>>>(histg, btot, nb);
    k_bscan  <<<1, 256, 0, stream>>>(btot, bstart, nb, E);
    k_place  <<<NBLK, 256, 0, stream>>>(ei, histg, bstart, st, nb, E, epb);
    k_local  <<<nb, 256, 0, stream>>>(st, bstart, base, deg, csr_src, N);
    k_node   <<<(N + 3) / 4, 256, 0, stream>>>(base, deg, csr_src, s_src, s_tgt, hb, out, N);
}